// Round 1
// baseline (2948.900 us; speedup 1.0000x reference)
//
#include <hip/hip_runtime.h>
#include <hip/hip_bf16.h>

// Problem constants
constexpr int kB = 512, kT = 128, kF = 256, kH = 384, kL = 3, kK = 10, kLab = 25;
constexpr int kCh = 128;            // H / L
constexpr int kGates = 1542;        // 4H + 2L
constexpr int kKin = 640;           // F + H (t-flag folded into bias)
constexpr int kNch = 20;            // kKin / 32
constexpr int kNsw = 528;           // 512 gate cols + 6 logit cols + 10 zero pad

typedef short bf16x8 __attribute__((ext_vector_type(8)));
typedef float f32x4 __attribute__((ext_vector_type(4)));

__device__ __forceinline__ float sigm(float x) { return 1.f / (1.f + __expf(-x)); }

// ---------------------------------------------------------------------------
// Prologue: build swizzled bf16 weights, bias vectors, transposed bf16 X,
// transposed conv weights (W2), zero-init h[0] and c state.
// Wsw layout: [l][chunk c][n][32]  where the 32 = k within chunk (frag order),
//   n<512 -> gate col (gate = n>>7, ch = n&127), n in [512,518) -> logit col,
//   n >= 518 -> zero.
// ---------------------------------------------------------------------------
__global__ void prep_kernel(const float* __restrict__ X,
                            const float* __restrict__ kernel_w,
                            const float* __restrict__ kernel_b,
                            const float* __restrict__ rec_w,
                            const float* __restrict__ rec_b,
                            const float* __restrict__ conv_w,
                            __hip_bfloat16* __restrict__ Wsw,
                            float* __restrict__ bias,
                            __hip_bfloat16* __restrict__ Xbf,
                            float* __restrict__ W2,
                            __hip_bfloat16* __restrict__ Hh,
                            float* __restrict__ Cst) {
  const long ntot = (long)kT * kB * kF;  // 16,777,216 covers all jobs
  const long stride = (long)gridDim.x * blockDim.x;
  for (long i = (long)blockIdx.x * blockDim.x + threadIdx.x; i < ntot; i += stride) {
    // ---- Xbf: (T,B,F) bf16 from X (B,T,F) fp32
    {
      int f = (int)(i % kF);
      long bt = i / kF;
      int b = (int)(bt % kB);
      int t = (int)(bt / kB);
      Xbf[i] = __float2bfloat16(X[((long)b * kT + t) * kF + f]);
    }
    // ---- Wsw: 3*20*528*32 = 1,013,760
    if (i < 3L * kNch * kNsw * 32) {
      int j = (int)(i & 31);
      long r = i >> 5;
      int n = (int)(r % kNsw);
      long r2 = r / kNsw;
      int c = (int)(r2 % kNch);
      int l = (int)(r2 / kNch);
      int k = c * 32 + j;
      float v = 0.f;
      int gcol = -1;
      if (n < 512) gcol = 6 + ((n >> 7) * 3 + l) * kCh + (n & 127);
      else if (n < 518) gcol = n - 512;
      if (gcol >= 0)
        v = (k < kF) ? kernel_w[(long)k * kGates + gcol]
                     : rec_w[(long)(k - kF) * kGates + gcol];
      Wsw[i] = __float2bfloat16(v);
    }
    // ---- W2: (3840, 384): W2[k*384+h][o] = conv_w[o][h][k]
    if (i < (long)kH * kK * kH) {
      int o = (int)(i % kH);
      long kk = i / kH;
      int h = (int)(kk % kH);
      int k = (int)(kk / kH);
      W2[i] = conv_w[((long)o * kH + h) * kK + k];
    }
    // ---- bias (two variants: t==0 and t>0)
    if (i < kGates) {
      float b0 = kernel_b[i] + rec_b[i];
      bias[i] = b0;
      bias[kGates + i] = b0 + kernel_w[(long)kF * kGates + i] + rec_w[(long)kH * kGates + i];
    }
    // ---- zero h_{-1} and c state
    if (i < (long)kB * kH) {
      Hh[i] = __float2bfloat16(0.f);
      Cst[i] = 0.f;
    }
  }
}

// ---------------------------------------------------------------------------
// One fused kernel per timestep: GEMM (M=512,N=1542,K=640, bf16 MFMA) + cumax
// logits + cell update. Grid (32 Mtiles, 3 l). Block 256 = 4 waves; wave w owns
// ch in [w*32, w*32+32) for all 4 gate groups -> cell is wave-local.
// ---------------------------------------------------------------------------
__global__ __launch_bounds__(256) void step_kernel(
    const __hip_bfloat16* __restrict__ Wsw, const float* __restrict__ bias,
    const __hip_bfloat16* __restrict__ Xbf, __hip_bfloat16* __restrict__ Hh,
    float* __restrict__ Cst, float* __restrict__ Dhist, int step) {
  const int mt = blockIdx.x, l = blockIdx.y;
  const int tid = threadIdx.x;
  const int lane = tid & 63, wave = tid >> 6;
  const int r16 = lane & 15, quad = lane >> 4;
  const int brow = mt * 16 + r16;

  const float* bt = bias + (step > 0 ? kGates : 0);

  f32x4 acc[8];
#pragma unroll
  for (int i = 0; i < 8; ++i) acc[i] = (f32x4){0.f, 0.f, 0.f, 0.f};
  f32x4 accL = (f32x4){0.f, 0.f, 0.f, 0.f};

  const __hip_bfloat16* Wl = Wsw + (size_t)l * (kNch * kNsw * 32);
  const __hip_bfloat16* Xrow = Xbf + ((size_t)step * kB + brow) * kF;
  const __hip_bfloat16* Hrow = Hh + ((size_t)step * kB + brow) * kH;

  for (int c = 0; c < kNch; ++c) {
    const __hip_bfloat16* wp = Wl + (size_t)c * (kNsw * 32);
    bf16x8 af;
    if (c < 8)
      af = *(const bf16x8*)(Xrow + c * 32 + quad * 8);
    else
      af = *(const bf16x8*)(Hrow + (c - 8) * 32 + quad * 8);
#pragma unroll
    for (int ti = 0; ti < 8; ++ti) {
      int gt = ti >> 1, s = ti & 1;
      int n0 = gt * kCh + wave * 32 + s * 16;
      bf16x8 bf = *(const bf16x8*)(wp + (n0 + r16) * 32 + quad * 8);
      acc[ti] = __builtin_amdgcn_mfma_f32_16x16x32_bf16(af, bf, acc[ti], 0, 0, 0);
    }
    if (wave == 0) {
      bf16x8 bf = *(const bf16x8*)(wp + (512 + r16) * 32 + quad * 8);
      accL = __builtin_amdgcn_mfma_f32_16x16x32_bf16(af, bf, accL, 0, 0, 0);
    }
  }

  __shared__ float Lg[16][6];
  __shared__ float fmS[16], imS[16];
  if (wave == 0 && r16 < 6) {
#pragma unroll
    for (int r = 0; r < 4; ++r) Lg[quad * 4 + r][r16] = accL[r] + bt[r16];
  }
  __syncthreads();
  if (tid < 16) {
    float z0 = Lg[tid][0], z1 = Lg[tid][1], z2 = Lg[tid][2];
    float m = fmaxf(z0, fmaxf(z1, z2));
    float e0 = __expf(z0 - m), e1 = __expf(z1 - m), e2 = __expf(z2 - m);
    float inv = 1.f / (e0 + e1 + e2);
    float fm0 = e0 * inv, fm1 = (e0 + e1) * inv, fm2 = 1.f;
    float z3 = Lg[tid][3], z4 = Lg[tid][4], z5 = Lg[tid][5];
    float m2 = fmaxf(z3, fmaxf(z4, z5));
    float e3 = __expf(z3 - m2), e4 = __expf(z4 - m2), e5 = __expf(z5 - m2);
    float inv2 = 1.f / (e3 + e4 + e5);
    float im0 = 1.f, im1 = (e4 + e5) * inv2, im2 = e5 * inv2;
    float fmarr[3] = {fm0, fm1, fm2}, imarr[3] = {im0, im1, im2};
    fmS[tid] = fmarr[l];
    imS[tid] = imarr[l];
    // identical value written by all 3 l-blocks (benign)
    Dhist[(size_t)step * kB + mt * 16 + tid] = 1.f - (fm0 + fm1 + fm2) * (1.f / 3.f);
  }
  __syncthreads();

  __hip_bfloat16* Hout = Hh + (size_t)(step + 1) * kB * kH;
#pragma unroll
  for (int s = 0; s < 2; ++s) {
    int chs = wave * 32 + s * 16 + r16;
    float bF = bt[6 + (0 * 3 + l) * kCh + chs];
    float bI = bt[6 + (1 * 3 + l) * kCh + chs];
    float bO = bt[6 + (2 * 3 + l) * kCh + chs];
    float bC = bt[6 + (3 * 3 + l) * kCh + chs];
#pragma unroll
    for (int r = 0; r < 4; ++r) {
      int rowl = quad * 4 + r;
      int b = mt * 16 + rowl;
      float fg = sigm(acc[0 + s][r] + bF);
      float ig = sigm(acc[2 + s][r] + bI);
      float og = sigm(acc[4 + s][r] + bO);
      float ci = tanhf(acc[6 + s][r] + bC);
      float fmv = fmS[rowl], imv = imS[rowl], ov = fmv * imv;
      size_t idx = (size_t)b * kH + l * kCh + chs;
      float co = Cst[idx];
      float cn = ov * (fg * co + ig * ci) + (fmv - ov) * co + (imv - ov) * ci;
      Cst[idx] = cn;
      Hout[idx] = __float2bfloat16(og * tanhf(cn));
    }
  }
}

// ---------------------------------------------------------------------------
// Epilogue 1: per-b local_dis softmax, Z = ld[k]*h_s, theme, hbase, ConvO init
// ---------------------------------------------------------------------------
__global__ void epi1_kernel(const int* __restrict__ vlen,
                            const float* __restrict__ Dhist,
                            const __hip_bfloat16* __restrict__ Hh,
                            const float* __restrict__ conv_b,
                            float* __restrict__ Z, float* __restrict__ theme,
                            float* __restrict__ hbase, float* __restrict__ ConvO) {
  int b = blockIdx.x, tid = threadIdx.x;
  int tb = vlen[b] - 1;
  float d[kK], ld[kK];
  float run = 0.f;
#pragma unroll
  for (int k = 0; k < kK; ++k) {
    int s = tb - (kK - 1) + k;
    float dv = (s >= 0) ? Dhist[(size_t)s * kB + b] : 0.f;
    run += dv;
    d[k] = run;
  }
  float m = d[0];
#pragma unroll
  for (int k = 1; k < kK; ++k) m = fmaxf(m, d[k]);
  float se = 0.f;
#pragma unroll
  for (int k = 0; k < kK; ++k) {
    ld[k] = __expf(d[k] - m);
    se += ld[k];
  }
  float inv = 1.f / se;
#pragma unroll
  for (int k = 0; k < kK; ++k) ld[k] *= inv;

  for (int h = tid; h < kH; h += blockDim.x) {
    float th = 0.f;
#pragma unroll
    for (int k = 0; k < kK; ++k) {
      int s = tb - (kK - 1) + k;
      float hv = (s >= 0) ? __bfloat162float(Hh[((size_t)(s + 1) * kB + b) * kH + h]) : 0.f;
      float z = ld[k] * hv;
      Z[((size_t)b * kK + k) * kH + h] = z;
      th += z;
    }
    theme[(size_t)b * kH + h] = th * (1.f / kK);
    hbase[(size_t)b * kH + h] = __bfloat162float(Hh[((size_t)(tb + 1) * kB + b) * kH + h]);
    ConvO[(size_t)b * kH + h] = conv_b[h];
  }
}

// Epilogue 2: U = relu(theme @ scale_w + scale_b)   (512 x 64)
__global__ void epi2_kernel(const float* __restrict__ theme,
                            const float* __restrict__ scale_w,
                            const float* __restrict__ scale_b, float* __restrict__ U) {
  int b = blockIdx.x, o = threadIdx.x;  // 64 threads
  __shared__ float tr[kH];
  for (int h = o; h < kH; h += 64) tr[h] = theme[(size_t)b * kH + h];
  __syncthreads();
  float a = scale_b[o];
  for (int h = 0; h < kH; ++h) a += tr[h] * scale_w[(size_t)h * 64 + o];
  U[(size_t)b * 64 + o] = fmaxf(a, 0.f);
}

// Epilogue 3: V = sigmoid(U @ rescale_w + rescale_b)   (512 x 384)
__global__ void epi3_kernel(const float* __restrict__ U,
                            const float* __restrict__ rescale_w,
                            const float* __restrict__ rescale_b, float* __restrict__ V) {
  int b = blockIdx.x, tid = threadIdx.x;  // 128 threads
  __shared__ float ur[64];
  if (tid < 64) ur[tid] = U[(size_t)b * 64 + tid];
  __syncthreads();
  for (int o = tid; o < kH; o += 128) {
    float a = rescale_b[o];
#pragma unroll
    for (int k = 0; k < 64; ++k) a += ur[k] * rescale_w[(size_t)k * kH + o];
    V[(size_t)b * kH + o] = sigm(a);
  }
}

// Epilogue 4: ConvO += Z(512x3840) @ W2(3840x384), K-split x8 with atomics
__global__ void epi4_kernel(const float* __restrict__ Z, const float* __restrict__ W2,
                            float* __restrict__ ConvO) {
  const int mt = blockIdx.x, nt = blockIdx.y, kc = blockIdx.z;
  const int tx = threadIdx.x % 16, ty = threadIdx.x / 16;
  __shared__ float Zs[64][33];
  __shared__ float Ws[32][65];
  float acc[4][4];
#pragma unroll
  for (int i = 0; i < 4; ++i)
#pragma unroll
    for (int j = 0; j < 4; ++j) acc[i][j] = 0.f;
  const int b0 = mt * 64, o0 = nt * 64, k0 = kc * 480;
  for (int kk = 0; kk < 480; kk += 32) {
    for (int i = threadIdx.x; i < 64 * 32; i += 256) {
      int rr = i / 32, cc = i % 32;
      Zs[rr][cc] = Z[(size_t)(b0 + rr) * (kK * kH) + k0 + kk + cc];
    }
    for (int i = threadIdx.x; i < 32 * 64; i += 256) {
      int rr = i / 64, cc = i % 64;
      Ws[rr][cc] = W2[(size_t)(k0 + kk + rr) * kH + o0 + cc];
    }
    __syncthreads();
#pragma unroll
    for (int k = 0; k < 32; ++k)
#pragma unroll
      for (int i = 0; i < 4; ++i)
#pragma unroll
        for (int j = 0; j < 4; ++j)
          acc[i][j] += Zs[ty * 4 + i][k] * Ws[k][tx * 4 + j];
    __syncthreads();
  }
#pragma unroll
  for (int i = 0; i < 4; ++i)
#pragma unroll
    for (int j = 0; j < 4; ++j)
      atomicAdd(&ConvO[(size_t)(b0 + ty * 4 + i) * kH + o0 + tx * 4 + j], acc[i][j]);
}

// Epilogue 5: out[b] = (V*ConvO + hbase) @ out_w + out_b
__global__ void epi5_kernel(const float* __restrict__ V, const float* __restrict__ ConvO,
                            const float* __restrict__ hbase,
                            const float* __restrict__ out_w,
                            const float* __restrict__ out_b, float* __restrict__ out) {
  int b = blockIdx.x, tid = threadIdx.x;  // 64 threads
  __shared__ float r[kH];
  for (int h = tid; h < kH; h += 64)
    r[h] = V[(size_t)b * kH + h] * ConvO[(size_t)b * kH + h] + hbase[(size_t)b * kH + h];
  __syncthreads();
  if (tid < kLab) {
    float a = out_b[tid];
    for (int h = 0; h < kH; ++h) a += r[h] * out_w[(size_t)h * kLab + tid];
    out[(size_t)b * kLab + tid] = a;
  }
}

extern "C" void kernel_launch(void* const* d_in, const int* in_sizes, int n_in,
                              void* d_out, int out_size, void* d_ws, size_t ws_size,
                              hipStream_t stream) {
  (void)in_sizes; (void)n_in; (void)out_size; (void)ws_size;
  const float* X = (const float*)d_in[0];
  const int* vlen = (const int*)d_in[1];
  const float* kernel_w = (const float*)d_in[2];
  const float* kernel_b = (const float*)d_in[3];
  const float* rec_w = (const float*)d_in[4];
  const float* rec_b = (const float*)d_in[5];
  const float* scale_w = (const float*)d_in[6];
  const float* scale_b = (const float*)d_in[7];
  const float* rescale_w = (const float*)d_in[8];
  const float* rescale_b = (const float*)d_in[9];
  const float* conv_w = (const float*)d_in[10];
  const float* conv_b = (const float*)d_in[11];
  const float* out_w = (const float*)d_in[12];
  const float* out_b = (const float*)d_in[13];
  float* out = (float*)d_out;

  char* ws = (char*)d_ws;
  size_t off = 0;
  auto alloc = [&](size_t bytes) -> void* {
    void* p = ws + off;
    off += (bytes + 255) & ~(size_t)255;
    return p;
  };
  __hip_bfloat16* Wsw = (__hip_bfloat16*)alloc((size_t)3 * kNch * kNsw * 32 * 2);
  float* bias = (float*)alloc((size_t)2 * kGates * 4);
  __hip_bfloat16* Xbf = (__hip_bfloat16*)alloc((size_t)kT * kB * kF * 2);
  __hip_bfloat16* Hh = (__hip_bfloat16*)alloc((size_t)(kT + 1) * kB * kH * 2);
  float* Cst = (float*)alloc((size_t)kB * kH * 4);
  float* Dhist = (float*)alloc((size_t)kT * kB * 4);
  float* Z = (float*)alloc((size_t)kB * kK * kH * 4);
  float* W2 = (float*)alloc((size_t)kK * kH * kH * 4);
  float* theme = (float*)alloc((size_t)kB * kH * 4);
  float* hbase = (float*)alloc((size_t)kB * kH * 4);
  float* U = (float*)alloc((size_t)kB * 64 * 4);
  float* V = (float*)alloc((size_t)kB * kH * 4);
  float* ConvO = (float*)alloc((size_t)kB * kH * 4);

  hipLaunchKernelGGL(prep_kernel, dim3(16384), dim3(256), 0, stream, X, kernel_w,
                     kernel_b, rec_w, rec_b, conv_w, Wsw, bias, Xbf, W2, Hh, Cst);

  for (int t = 0; t < kT; ++t) {
    hipLaunchKernelGGL(step_kernel, dim3(32, 3), dim3(256), 0, stream, Wsw, bias,
                       Xbf, Hh, Cst, Dhist, t);
  }

  hipLaunchKernelGGL(epi1_kernel, dim3(kB), dim3(128), 0, stream, vlen, Dhist, Hh,
                     conv_b, Z, theme, hbase, ConvO);
  hipLaunchKernelGGL(epi2_kernel, dim3(kB), dim3(64), 0, stream, theme, scale_w,
                     scale_b, U);
  hipLaunchKernelGGL(epi3_kernel, dim3(kB), dim3(128), 0, stream, U, rescale_w,
                     rescale_b, V);
  hipLaunchKernelGGL(epi4_kernel, dim3(8, 6, 8), dim3(256), 0, stream, Z, W2, ConvO);
  hipLaunchKernelGGL(epi5_kernel, dim3(kB), dim3(64), 0, stream, V, ConvO, hbase,
                     out_w, out_b, out);
}